// Round 1
// baseline (77.788 us; speedup 1.0000x reference)
//
#include <hip/hip_runtime.h>

// out[b,c,d,h,w] = in[b,0,d, clamp(h+dy,0,H-1), clamp(w+dx,0,W-1)]
// (dy,dx) per channel: c0:(-1,-1) c1:(0,0) c2:(+1,+1) c3:(+1,-1) c4:(-1,+1)
// B=2, D=48, H=256, W=512, f32. Memory-bound streaming gather.

__global__ __launch_bounds__(256) void prop_kernel(
    const float* __restrict__ in, float* __restrict__ out, long long total4) {
    constexpr int D = 48, H = 256, W = 512;
    constexpr int W4 = W / 4;
    const long long planeDHW = (long long)D * H * W;  // per (b,c) volume

    for (long long idx = (long long)blockIdx.x * blockDim.x + threadIdx.x;
         idx < total4;
         idx += (long long)gridDim.x * blockDim.x) {
        // decompose: idx = ((b*D + d)*H + h)*W4 + w4
        int w4 = (int)(idx & (W4 - 1));          // W4 = 128
        long long t = idx >> 7;
        int h = (int)(t & (H - 1));              // H = 256
        t >>= 8;
        int d = (int)(t % D);
        int b = (int)(t / D);

        const int w0 = w4 * 4;
        const float* base = in + ((long long)b * D + d) * (long long)(H * W);
        const int hm = h > 0 ? h - 1 : 0;
        const int hp = h < H - 1 ? h + 1 : H - 1;
        const float* rowm = base + (long long)hm * W;
        const float* row0 = base + (long long)h * W;
        const float* rowp = base + (long long)hp * W;

        // m[j] = rowm[clamp(w0-1+j)], p[j] = rowp[clamp(w0-1+j)], j=0..5
        float m[6], p[6], c[4];
        if (w0 >= 4 && w0 + 4 < W) {
            // interior fast path: aligned float4 + 2 scalar edges per shifted row
            float4 mv = *reinterpret_cast<const float4*>(rowm + w0);
            m[0] = rowm[w0 - 1]; m[1] = mv.x; m[2] = mv.y; m[3] = mv.z; m[4] = mv.w;
            m[5] = rowm[w0 + 4];
            float4 pv = *reinterpret_cast<const float4*>(rowp + w0);
            p[0] = rowp[w0 - 1]; p[1] = pv.x; p[2] = pv.y; p[3] = pv.z; p[4] = pv.w;
            p[5] = rowp[w0 + 4];
            float4 cv = *reinterpret_cast<const float4*>(row0 + w0);
            c[0] = cv.x; c[1] = cv.y; c[2] = cv.z; c[3] = cv.w;
        } else {
            // W-boundary: clamped scalar loads
            #pragma unroll
            for (int j = 0; j < 6; ++j) {
                int w = w0 - 1 + j;
                w = w < 0 ? 0 : (w > W - 1 ? W - 1 : w);
                m[j] = rowm[w];
                p[j] = rowp[w];
            }
            #pragma unroll
            for (int j = 0; j < 4; ++j) c[j] = row0[w0 + j];
        }

        float* obase = out + (long long)b * 5 * planeDHW
                           + ((long long)d * H + h) * W + w0;
        // c0: (h-1, w-1) -> m[0..3]
        *reinterpret_cast<float4*>(obase)                = make_float4(m[0], m[1], m[2], m[3]);
        // c1: (h, w) -> c[0..3]
        *reinterpret_cast<float4*>(obase + planeDHW)     = make_float4(c[0], c[1], c[2], c[3]);
        // c2: (h+1, w+1) -> p[2..5]
        *reinterpret_cast<float4*>(obase + 2 * planeDHW) = make_float4(p[2], p[3], p[4], p[5]);
        // c3: (h+1, w-1) -> p[0..3]
        *reinterpret_cast<float4*>(obase + 3 * planeDHW) = make_float4(p[0], p[1], p[2], p[3]);
        // c4: (h-1, w+1) -> m[2..5]
        *reinterpret_cast<float4*>(obase + 4 * planeDHW) = make_float4(m[2], m[3], m[4], m[5]);
    }
}

extern "C" void kernel_launch(void* const* d_in, const int* in_sizes, int n_in,
                              void* d_out, int out_size, void* d_ws, size_t ws_size,
                              hipStream_t stream) {
    const float* in = (const float*)d_in[0];
    float* out = (float*)d_out;

    // total float4 groups over (b,d,h,w4): 2*48*256*128 = 3,145,728
    const long long total4 = 2LL * 48 * 256 * 128;
    const int block = 256;
    int grid = 2048;  // memory-bound: cap and grid-stride (G11)
    prop_kernel<<<grid, block, 0, stream>>>(in, out, total4);
}

// Round 2
// 56.600 us; speedup vs baseline: 1.3744x; 1.3744x over previous
//
#include <hip/hip_runtime.h>

// out[b,c,d,h,w] = in[b,0,d, clamp(h+dy,0,H-1), clamp(w+dx,0,W-1)]
// (dy,dx): c0:(-1,-1) c1:(0,0) c2:(+1,+1) c3:(+1,-1) c4:(-1,+1)
// B=2, D=48, H=256, W=512 f32.
//
// R2: VMEM-issue-bound fix. Each thread produces HB=4 output rows at one
// float4 w-slot: loads the 6-row halo window ONCE (6 float4 loads -> 20
// float4 stores), and gets the w-1 / w+4 halo values from neighbor lanes
// via __shfl_up/__shfl_down (1 fallback scalar load per wave per row at the
// wave seam). 1.3 VMEM insts/store vs 2.4 before.

constexpr int D = 48, H = 256, W = 512;
constexpr int W4 = W / 4;     // 128: two waves cover one full row
constexpr int HB = 4;         // output rows per thread

__global__ __launch_bounds__(256) void prop_kernel(
    const float* __restrict__ in, float* __restrict__ out) {
    const int w4   = threadIdx.x & (W4 - 1);   // 0..127
    const int hgrp = threadIdx.x >> 7;         // 0..1 (two h-groups per block)
    const int lane = threadIdx.x & 63;

    int blk = blockIdx.x;
    const int h8 = blk & 31;                   // H / (2*HB) = 32 h-blocks
    blk >>= 5;
    const int d = blk % D;
    const int b = blk / D;

    const int h0 = h8 * (2 * HB) + hgrp * HB;  // first output row
    const int w0 = w4 * 4;

    const float* base = in + (b * D + d) * (H * W);

    // Load 6-row window [h0-1 .. h0+4] (clamped), with L/R halo via shuffle.
    float4 v[6];
    float  L[6], R[6];
    #pragma unroll
    for (int i = 0; i < 6; ++i) {
        int r = h0 - 1 + i;
        r = r < 0 ? 0 : (r > H - 1 ? H - 1 : r);
        const float* row = base + r * W;
        float4 t = *reinterpret_cast<const float4*>(row + w0);
        float l  = __shfl_up(t.w, 1);          // lane i-1's w0+3 == our w0-1
        float rr = __shfl_down(t.x, 1);        // lane i+1's w0   == our w0+4
        if (w4 == 0)          l  = t.x;        // clamp at W edge
        else if (lane == 0)   l  = row[w0 - 1];    // wave seam fallback
        if (w4 == W4 - 1)     rr = t.w;        // clamp at W edge
        else if (lane == 63)  rr = row[w0 + 4];    // wave seam fallback
        v[i] = t; L[i] = l; R[i] = rr;
    }

    // out index: (((b*5 + c)*D + d)*H + h)*W + w   (all fit in int: <63M)
    const int planeDHW = D * H * W;            // 6,291,456
    float* o0 = out + ((b * 5) * D + d) * (H * W) + h0 * W + w0;

    #pragma unroll
    for (int j = 0; j < HB; ++j) {
        const int m = j, c = j + 1, p = j + 2; // window rows: h-1, h, h+1
        float* ob = o0 + j * W;
        // c0: row h-1, w-1..w+2
        *reinterpret_cast<float4*>(ob)                 = make_float4(L[m], v[m].x, v[m].y, v[m].z);
        // c1: row h, w..w+3
        *reinterpret_cast<float4*>(ob + planeDHW)      = v[c];
        // c2: row h+1, w+1..w+4
        *reinterpret_cast<float4*>(ob + 2 * planeDHW)  = make_float4(v[p].y, v[p].z, v[p].w, R[p]);
        // c3: row h+1, w-1..w+2
        *reinterpret_cast<float4*>(ob + 3 * planeDHW)  = make_float4(L[p], v[p].x, v[p].y, v[p].z);
        // c4: row h-1, w+1..w+4
        *reinterpret_cast<float4*>(ob + 4 * planeDHW)  = make_float4(v[m].y, v[m].z, v[m].w, R[m]);
    }
}

extern "C" void kernel_launch(void* const* d_in, const int* in_sizes, int n_in,
                              void* d_out, int out_size, void* d_ws, size_t ws_size,
                              hipStream_t stream) {
    const float* in = (const float*)d_in[0];
    float* out = (float*)d_out;

    // grid: B * D * (H / 8) = 2 * 48 * 32 = 3072 blocks, exact cover
    const int grid = 2 * D * (H / (2 * HB));
    prop_kernel<<<grid, 256, 0, stream>>>(in, out);
}

// Round 4
// 53.545 us; speedup vs baseline: 1.4528x; 1.0571x over previous
//
#include <hip/hip_runtime.h>

// out[b,c,d,h,w] = in[b,0,d, clamp(h+dy,0,H-1), clamp(w+dx,0,W-1)]
// (dy,dx): c0:(-1,-1) c1:(0,0) c2:(+1,+1) c3:(+1,-1) c4:(-1,+1)
// B=2, D=48, H=256, W=512 f32.
//
// R4 = R3 with the nontemporal-store type fixed (clang ext_vector, not
// HIP_vector_type). HB=8 rows/thread (10 window-row loads -> 40 stores,
// load redundancy 1.25x), channel-major store order (8KB/wave contiguous
// bursts per stream), nontemporal stores (output ~= L3 size; keep input
// cached for the h-halo re-reads).

typedef float f32x4 __attribute__((ext_vector_type(4)));

constexpr int D = 48, H = 256, W = 512;
constexpr int W4 = W / 4;     // 128: two waves cover one full row
constexpr int HB = 8;         // output rows per thread

__device__ __forceinline__ void nt_store4(float* p, float a, float b, float c, float d) {
    f32x4 v = {a, b, c, d};
    __builtin_nontemporal_store(v, reinterpret_cast<f32x4*>(p));
}

__global__ __launch_bounds__(256) void prop_kernel(
    const float* __restrict__ in, float* __restrict__ out) {
    const int w4   = threadIdx.x & (W4 - 1);   // 0..127
    const int hgrp = threadIdx.x >> 7;         // 0..1 (two h-groups per block)
    const int lane = threadIdx.x & 63;

    int blk = blockIdx.x;
    const int h16 = blk & 15;                  // H / (2*HB) = 16 h-blocks
    blk >>= 4;
    const int d = blk % D;
    const int b = blk / D;

    const int h0 = h16 * (2 * HB) + hgrp * HB; // first output row
    const int w0 = w4 * 4;

    const float* base = in + (b * D + d) * (H * W);

    // Load (HB+2)-row window [h0-1 .. h0+HB] (clamped); L/R halo via shuffle.
    float4 v[HB + 2];
    float  L[HB + 2], R[HB + 2];
    #pragma unroll
    for (int i = 0; i < HB + 2; ++i) {
        int r = h0 - 1 + i;
        r = r < 0 ? 0 : (r > H - 1 ? H - 1 : r);
        const float* row = base + r * W;
        float4 t = *reinterpret_cast<const float4*>(row + w0);
        float l  = __shfl_up(t.w, 1);          // lane i-1's w0+3 == our w0-1
        float rr = __shfl_down(t.x, 1);        // lane i+1's w0   == our w0+4
        if (w4 == 0)          l  = t.x;        // clamp at W edge
        else if (lane == 0)   l  = row[w0 - 1];    // wave seam fallback
        if (w4 == W4 - 1)     rr = t.w;        // clamp at W edge
        else if (lane == 63)  rr = row[w0 + 4];    // wave seam fallback
        v[i] = t; L[i] = l; R[i] = rr;
    }

    const int planeDHW = D * H * W;            // 6,291,456
    float* o0 = out + ((b * 5) * D + d) * (H * W) + h0 * W + w0;

    // Channel-major stores: per channel, HB consecutive rows (contiguous
    // 1KB/wave lines, 8KB burst per stream) before switching streams.
    #pragma unroll
    for (int j = 0; j < HB; ++j) {  // c0: row h-1, w-1..w+2
        const int m = j;
        nt_store4(o0 + j * W, L[m], v[m].x, v[m].y, v[m].z);
    }
    #pragma unroll
    for (int j = 0; j < HB; ++j) {  // c1: row h, w..w+3
        const int c = j + 1;
        nt_store4(o0 + planeDHW + j * W, v[c].x, v[c].y, v[c].z, v[c].w);
    }
    #pragma unroll
    for (int j = 0; j < HB; ++j) {  // c2: row h+1, w+1..w+4
        const int p = j + 2;
        nt_store4(o0 + 2 * planeDHW + j * W, v[p].y, v[p].z, v[p].w, R[p]);
    }
    #pragma unroll
    for (int j = 0; j < HB; ++j) {  // c3: row h+1, w-1..w+2
        const int p = j + 2;
        nt_store4(o0 + 3 * planeDHW + j * W, L[p], v[p].x, v[p].y, v[p].z);
    }
    #pragma unroll
    for (int j = 0; j < HB; ++j) {  // c4: row h-1, w+1..w+4
        const int m = j;
        nt_store4(o0 + 4 * planeDHW + j * W, v[m].y, v[m].z, v[m].w, R[m]);
    }
}

extern "C" void kernel_launch(void* const* d_in, const int* in_sizes, int n_in,
                              void* d_out, int out_size, void* d_ws, size_t ws_size,
                              hipStream_t stream) {
    const float* in = (const float*)d_in[0];
    float* out = (float*)d_out;

    // grid: B * D * (H / 16) = 2 * 48 * 16 = 1536 blocks, exact cover
    const int grid = 2 * D * (H / (2 * HB));
    prop_kernel<<<grid, 256, 0, stream>>>(in, out);
}